// Round 3
// baseline (995.051 us; speedup 1.0000x reference)
//
#include <hip/hip_runtime.h>
#include <cstdint>

// Problem: B=64, T=512, I=K=1024, H=1024.
// Reference collapses to: rtot_z = h0@R_z^T + rb_z + b_z  (z in {f,i,g}; o-gate dead)
//   gate_z[m',h] = x_perm[m'] . W_z^T + rtot_z[b,h]   with m' = t*64 + b
//   c = sig(f)*c0 + sig(i)*tanh(g); hidden[h, m'] = tanh(c); last-t -> h_last, c_last.
// Dtype is detected at runtime (fp32 vs bf16) from x's bit patterns — see detect_f32.
// This round: NO global_load_lds (suspect in R1/R2 NaN) — plain register staging.

typedef short s16x8 __attribute__((ext_vector_type(8)));
typedef short s16x4 __attribute__((ext_vector_type(4)));
typedef float f32x4 __attribute__((ext_vector_type(4)));

static __device__ __forceinline__ float bf2f(unsigned short u) {
    union { unsigned int i; float f; } v; v.i = ((unsigned int)u) << 16; return v.f;
}
static __device__ __forceinline__ unsigned short f2bf(float f) {
    union { float f; unsigned int i; } v; v.f = f;
    unsigned int u = v.i;
    return (unsigned short)((u + 0x7fffu + ((u >> 16) & 1u)) >> 16);
}
static __device__ __forceinline__ float sigm_(float x) { return 1.0f / (1.0f + __expf(-x)); }
static __device__ __forceinline__ float tanh_(float x) { return 1.0f - 2.0f / (1.0f + __expf(2.0f * x)); }

// Detect fp32 vs bf16 storage: fp32 N(0,1) values have exponent-field in ~[100,140].
// Packed bf16 pairs put (exp&0x7F)<<1|mant6 of the HIGH bf16 there -> {236..255}u{0..9}.
// Deterministic, wave-uniform (all threads read the same 16 dwords).
static __device__ __forceinline__ int detect_f32(const void* x) {
    const unsigned int* u = (const unsigned int*)x;
    int c = 0;
#pragma unroll
    for (int i = 0; i < 16; ++i) {
        unsigned int e = (u[i] >> 23) & 255u;
        c += (e >= 100u && e <= 140u) ? 1 : 0;
    }
    return c >= 8;
}

// Load 8 consecutive elements at element-offset eoff as bf16 bits (converting if fp32)
// and store to LDS via a plain typed pointer (guaranteed-correct ds_write path).
static __device__ __forceinline__ void stage8(const void* base, size_t eoff, short* dst, int f32) {
    if (f32) {
        const float* s = (const float*)base + eoff;
        float4 u0 = *(const float4*)s;
        float4 u1 = *(const float4*)(s + 4);
        s16x8 v;
        v[0] = (short)f2bf(u0.x); v[1] = (short)f2bf(u0.y);
        v[2] = (short)f2bf(u0.z); v[3] = (short)f2bf(u0.w);
        v[4] = (short)f2bf(u1.x); v[5] = (short)f2bf(u1.y);
        v[6] = (short)f2bf(u1.z); v[7] = (short)f2bf(u1.w);
        *(s16x8*)dst = v;
    } else {
        *(s16x8*)dst = *(const s16x8*)((const unsigned short*)base + eoff);
    }
}

static __device__ __forceinline__ float ldsc(const void* p, int i, int f32) {
    return f32 ? ((const float*)p)[i] : bf2f(((const unsigned short*)p)[i]);
}

// ---------------- rtot precompute: rt[z][b][h] = h0[b] . R_z[h] + rb_z[h] + b_z[h] -------------
__global__ __launch_bounds__(256) void rprep_kernel(
    const void* __restrict__ xdet,
    const void* __restrict__ h0,
    const void* __restrict__ Rf, const void* __restrict__ rbf, const void* __restrict__ bf_,
    const void* __restrict__ Ri, const void* __restrict__ rbi, const void* __restrict__ bi_,
    const void* __restrict__ Rg, const void* __restrict__ rbg, const void* __restrict__ bg_,
    float* __restrict__ rt)
{
    const int f32 = detect_f32(xdet);
    __shared__ float h0f[8][1024];   // 32 KB
    const int tid = threadIdx.x;
    const int b0 = blockIdx.y * 8;
    const int z  = blockIdx.z;
    for (int idx = tid; idx < 8 * 1024; idx += 256) {
        int r = idx >> 10, k = idx & 1023;
        h0f[r][k] = ldsc(h0, (b0 + r) * 1024 + k, f32);
    }
    __syncthreads();
    const void* R  = (z == 0) ? Rf  : (z == 1) ? Ri  : Rg;
    const void* rb = (z == 0) ? rbf : (z == 1) ? rbi : rbg;
    const void* bb = (z == 0) ? bf_ : (z == 1) ? bi_ : bg_;
    const int h = blockIdx.x * 256 + tid;
    float acc[8];
#pragma unroll
    for (int i = 0; i < 8; ++i) acc[i] = 0.f;
    for (int k0 = 0; k0 < 1024; k0 += 8) {
        float rf[8];
        if (f32) {
            const float* Rrow = (const float*)R + (size_t)h * 1024;
            float4 a = *(const float4*)(Rrow + k0);
            float4 b = *(const float4*)(Rrow + k0 + 4);
            rf[0] = a.x; rf[1] = a.y; rf[2] = a.z; rf[3] = a.w;
            rf[4] = b.x; rf[5] = b.y; rf[6] = b.z; rf[7] = b.w;
        } else {
            const unsigned short* Rrow = (const unsigned short*)R + (size_t)h * 1024;
            s16x8 rv = *(const s16x8*)(Rrow + k0);
#pragma unroll
            for (int j = 0; j < 8; ++j) rf[j] = bf2f((unsigned short)rv[j]);
        }
#pragma unroll
        for (int b = 0; b < 8; ++b) {
            float4 u0 = *(const float4*)&h0f[b][k0];
            float4 u1 = *(const float4*)&h0f[b][k0 + 4];
            acc[b] += rf[0] * u0.x + rf[1] * u0.y + rf[2] * u0.z + rf[3] * u0.w
                    + rf[4] * u1.x + rf[5] * u1.y + rf[6] * u1.z + rf[7] * u1.w;
        }
    }
    float extra = ldsc(rb, h, f32) + ldsc(bb, h, f32);
    float* outz = rt + (size_t)z * 65536;
#pragma unroll
    for (int b = 0; b < 8; ++b) outz[(b0 + b) * 1024 + h] = acc[b] + extra;
}

// ---------------- main fused GEMM + LSTM epilogue ----------------
// Tile: 128 m' x 64 h, 3 gate accumulators. 4 waves in 2x2 (wm, wn). BK=32.
__global__ __launch_bounds__(256, 2) void lstm_main(
    const void* __restrict__ x,      // [64][512][1024]
    const void* __restrict__ c0,     // [64][1024]
    const void* __restrict__ Wf,
    const void* __restrict__ Wi,
    const void* __restrict__ Wg,     // each [1024][1024]
    const float* __restrict__ rt,    // [3][64][1024] fp32 ws
    void* __restrict__ dout)         // hidden[1024][32768] | h[64][1024] | c[64][1024]
{
    // staging tiles (bf16 after conversion): A 8192 | Bf 4096 | Bi 4096 | Bg 4096 = 20480
    // epilogue transpose reuses smem: bf16 64x272=17408 or fp32 64x528=33792
    __shared__ __align__(16) unsigned char smem[33792];
    short* smA  = (short*)smem;              // [128 rows][32]
    short* smBf = (short*)(smem + 8192);     // [64 rows][32]
    short* smBi = (short*)(smem + 12288);
    short* smBg = (short*)(smem + 16384);

    const int f32 = detect_f32(x);
    const int tid  = threadIdx.x;
    const int lane = tid & 63;
    const int w    = tid >> 6;
    const int wm   = w >> 1;
    const int wn   = w & 1;
    const int col  = lane & 15;
    const int quad = lane >> 4;

    const int m0  = blockIdx.y * 128;
    const int h0t = blockIdx.x * 64;

    // ---- staging chunk assignment: 16B bf16 chunks (8 elems) ----
    // A: 512 chunks -> 2/thread; chunk c: row c>>2 (0..127), k-subchunk c&3
    const int cA0 = tid, cA1 = tid + 256;
    const int mgA0 = m0 + (cA0 >> 2), mgA1 = m0 + (cA1 >> 2);
    size_t aoff0 = (size_t)((mgA0 & 63) * 512 + (mgA0 >> 6)) * 1024 + (cA0 & 3) * 8;
    size_t aoff1 = (size_t)((mgA1 & 63) * 512 + (mgA1 >> 6)) * 1024 + (cA1 & 3) * 8;
    // B: 256 chunks/gate -> 1/thread; row tid>>2 (0..63)
    size_t boff = (size_t)(h0t + (tid >> 2)) * 1024 + (tid & 3) * 8;
    short* dA0 = smA  + cA0 * 8;
    short* dA1 = smA  + cA1 * 8;
    short* dBf = smBf + tid * 8;
    short* dBi = smBi + tid * 8;
    short* dBg = smBg + tid * 8;

    // ---- fragment read bases: row-major [row][32] bf16, 64B rows ----
    const short* aBase  = smA  + (wm * 64 + col) * 32 + quad * 8;
    const short* bfBase = smBf + (wn * 32 + col) * 32 + quad * 8;
    const short* biBase = smBi + (wn * 32 + col) * 32 + quad * 8;
    const short* bgBase = smBg + (wn * 32 + col) * 32 + quad * 8;

    f32x4 aF[4][2], aI[4][2], aG[4][2];
#pragma unroll
    for (int mi = 0; mi < 4; ++mi)
#pragma unroll
        for (int ni = 0; ni < 2; ++ni) {
            aF[mi][ni] = (f32x4)0.f; aI[mi][ni] = (f32x4)0.f; aG[mi][ni] = (f32x4)0.f;
        }

    for (int kt = 0; kt < 32; ++kt) {
        const size_t ko = (size_t)kt * 32;
        stage8(x,  aoff0 + ko, dA0, f32);
        stage8(x,  aoff1 + ko, dA1, f32);
        stage8(Wf, boff  + ko, dBf, f32);
        stage8(Wi, boff  + ko, dBi, f32);
        stage8(Wg, boff  + ko, dBg, f32);
        __syncthreads();

        s16x8 av[4], bfv[2], biv[2], bgv[2];
#pragma unroll
        for (int mi = 0; mi < 4; ++mi) av[mi] = *(const s16x8*)(aBase + mi * 512);
#pragma unroll
        for (int ni = 0; ni < 2; ++ni) {
            bfv[ni] = *(const s16x8*)(bfBase + ni * 512);
            biv[ni] = *(const s16x8*)(biBase + ni * 512);
            bgv[ni] = *(const s16x8*)(bgBase + ni * 512);
        }
#pragma unroll
        for (int mi = 0; mi < 4; ++mi)
#pragma unroll
            for (int ni = 0; ni < 2; ++ni) {
                aF[mi][ni] = __builtin_amdgcn_mfma_f32_16x16x32_bf16(av[mi], bfv[ni], aF[mi][ni], 0, 0, 0);
                aI[mi][ni] = __builtin_amdgcn_mfma_f32_16x16x32_bf16(av[mi], biv[ni], aI[mi][ni], 0, 0, 0);
                aG[mi][ni] = __builtin_amdgcn_mfma_f32_16x16x32_bf16(av[mi], bgv[ni], aG[mi][ni], 0, 0, 0);
            }
        __syncthreads();
    }

    // ---- epilogue ----
    const float* rtF = rt;
    const float* rtI = rt + 65536;
    const float* rtG = rt + 131072;
    unsigned short* outHb = (unsigned short*)dout;
    unsigned short* outHlb = outHb + 33554432;
    unsigned short* outClb = outHlb + 65536;
    float* outHf = (float*)dout;
    float* outHlf = outHf + 33554432;
    float* outClf = outHlf + 65536;

#pragma unroll
    for (int mi = 0; mi < 4; ++mi) {
#pragma unroll
        for (int ni = 0; ni < 2; ++ni) {
            const int hl = wn * 32 + ni * 16 + col;     // C col = N (h)
            const int h  = h0t + hl;
            const int mbase = wm * 64 + mi * 16 + quad * 4;  // C row = M (m')
            s16x4 packb;
            float4 packf;
#pragma unroll
            for (int r = 0; r < 4; ++r) {
                const int mg = m0 + mbase + r;
                const int b  = mg & 63;
                const int idx = b * 1024 + h;
                float pf = aF[mi][ni][r] + rtF[idx];
                float pi = aI[mi][ni][r] + rtI[idx];
                float pg = aG[mi][ni][r] + rtG[idx];
                float fv = sigm_(pf);
                float iv = sigm_(pi);
                float gv = tanh_(pg);
                float cv = fv * ldsc(c0, idx, f32) + iv * gv;
                float hv = tanh_(cv);
                if (r == 0) { packf.x = hv; } else if (r == 1) { packf.y = hv; }
                else if (r == 2) { packf.z = hv; } else { packf.w = hv; }
                packb[r] = (short)f2bf(hv);
                if ((mg >> 6) == 511) {          // t == T-1
                    if (f32) { outHlf[idx] = hv; outClf[idx] = cv; }
                    else     { outHlb[idx] = f2bf(hv); outClb[idx] = f2bf(cv); }
                }
            }
            if (f32) {
                float* ldsTf = (float*)(smem + (size_t)hl * 528);
                *(float4*)(ldsTf + mbase) = packf;
            } else {
                *(s16x4*)(smem + (size_t)hl * 272 + mbase * 2) = packb;
            }
        }
    }
    __syncthreads();

    const int hl = tid >> 2;                     // 0..63
    const int ch = tid & 3;                      // 32 m' each
    if (f32) {
        float* obase = outHf + (size_t)(h0t + hl) * 32768 + m0 + ch * 32;
        const unsigned char* trow = smem + (size_t)hl * 528 + ch * 128;
#pragma unroll
        for (int j = 0; j < 8; ++j)
            *(float4*)(obase + j * 4) = *(const float4*)(trow + j * 16);
    } else {
        unsigned short* obase = outHb + (size_t)(h0t + hl) * 32768 + m0 + ch * 32;
        const unsigned char* trow = smem + (size_t)hl * 272 + ch * 64;
#pragma unroll
        for (int j = 0; j < 4; ++j)
            *(s16x8*)(obase + j * 8) = *(const s16x8*)(trow + j * 16);
    }
}

extern "C" void kernel_launch(void* const* d_in, const int* in_sizes, int n_in,
                              void* d_out, int out_size, void* d_ws, size_t ws_size,
                              hipStream_t stream) {
    (void)in_sizes; (void)n_in; (void)out_size; (void)ws_size;
    const void* x   = d_in[0];
    const void* h0  = d_in[1];
    const void* c0  = d_in[2];
    const void* Wf  = d_in[3];
    const void* bf_ = d_in[4];
    const void* Rf  = d_in[5];
    const void* rbf = d_in[6];
    const void* Wi  = d_in[7];
    const void* bi_ = d_in[8];
    const void* Ri  = d_in[9];
    const void* rbi = d_in[10];
    const void* Wg  = d_in[11];
    const void* bg_ = d_in[12];
    const void* Rg  = d_in[13];
    const void* rbg = d_in[14];
    // d_in[15..18] = Wo, bo, Ro, rbo — dead in the reference, never read.

    float* rt = (float*)d_ws;                    // 3*64*1024 fp32 = 768 KB

    rprep_kernel<<<dim3(4, 8, 3), 256, 0, stream>>>(x, h0, Rf, rbf, bf_, Ri, rbi, bi_, Rg, rbg, bg_, rt);
    lstm_main<<<dim3(16, 256), 256, 0, stream>>>(x, c0, Wf, Wi, Wg, rt, d_out);
}